// Round 10
// baseline (392.507 us; speedup 1.0000x reference)
//
#include <hip/hip_runtime.h>
#include <hip/hip_fp16.h>

typedef __attribute__((ext_vector_type(8))) _Float16 f16x8;
typedef __attribute__((ext_vector_type(16))) float f32x16;

#define M_TOT 8192
#define N_TOT 8192
#define K_TOT 256
#define NBLK 768  // 3 blocks/CU x 256 CU -- co-resident by __launch_bounds__(256,3)

__device__ __forceinline__ void load_lds16(const void* g, void* l) {
  __builtin_amdgcn_global_load_lds(
      (const __attribute__((address_space(1))) unsigned int*)g,
      (__attribute__((address_space(3))) unsigned int*)l, 16, 0, 0);
}
__device__ __forceinline__ double shfl_xor_d(double v, int m) {
  unsigned long long u = (unsigned long long)__double_as_longlong(v);
  unsigned lo = (unsigned)u, hi = (unsigned)(u >> 32);
  lo = __shfl_xor(lo, m, 64);
  hi = __shfl_xor(hi, m, 64);
  return __longlong_as_double((long long)((((unsigned long long)hi) << 32) | lo));
}

// Two-generation grid barrier. Requires all NBLK blocks co-resident
// (guaranteed: grid==NBLK==3/CU x 256 CU, launch_bounds(256,3), 32KB LDS).
// Device-scope fences handle cross-XCD L2 visibility (G16).
__device__ __forceinline__ void grid_bar(unsigned* cnt, unsigned* sense, unsigned gen) {
  __syncthreads();
  if (threadIdx.x == 0) {
    __threadfence();  // release prior writes (L2 WB for cross-XCD)
    unsigned arrived =
        __hip_atomic_fetch_add(cnt, 1u, __ATOMIC_ACQ_REL, __HIP_MEMORY_SCOPE_AGENT) + 1;
    if (arrived == gen * NBLK) {
      __hip_atomic_store(sense, gen, __ATOMIC_RELEASE, __HIP_MEMORY_SCOPE_AGENT);
    } else {
      while (__hip_atomic_load(sense, __ATOMIC_ACQUIRE, __HIP_MEMORY_SCOPE_AGENT) < gen) {
      }
    }
    __threadfence();  // acquire (L1/L2 inv)
  }
  __syncthreads();
}

// ================= fused: prep -> barrier -> pmin-GEMM -> barrier -> refine ==========
__global__ __launch_bounds__(256, 3) void fused_kernel(
    const float* __restrict__ x, const float* __restrict__ embed,
    unsigned short* __restrict__ X0p, unsigned short* __restrict__ E0p,
    float* __restrict__ xsq, float* __restrict__ esq,
    unsigned short* __restrict__ pmin, unsigned* __restrict__ bar,
    float* __restrict__ out) {
  __shared__ unsigned short lds[16384];  // 32 KB (phase G only)

  const int tid = threadIdx.x;
  const int wid = tid >> 6;
  const int lane = tid & 63;

  // ---------------- phase P: row-wise fp16 convert + sq-norms ----------------
  // wave per row; rows 0..8191 = x, 8192..16383 = embed. 3072 waves total.
  for (int rw = blockIdx.x * 4 + wid; rw < 16384; rw += NBLK * 4) {
    const bool is_e = rw >= 8192;
    const int row = rw & 8191;
    const float* __restrict__ in = is_e ? embed : x;
    unsigned short* __restrict__ p0 = is_e ? E0p : X0p;
    float4 v = reinterpret_cast<const float4*>(in + (size_t)row * K_TOT)[lane];
    float f[4] = {v.x, v.y, v.z, v.w};
    unsigned short h[4];
#pragma unroll
    for (int c = 0; c < 4; ++c) h[c] = __half_as_ushort(__float2half_rn(f[c]));
    ushort4 o = {h[0], h[1], h[2], h[3]};
    reinterpret_cast<ushort4*>(p0 + (size_t)row * K_TOT)[lane] = o;
    float s = f[0] * f[0] + f[1] * f[1] + f[2] * f[2] + f[3] * f[3];
#pragma unroll
    for (int off = 32; off > 0; off >>= 1) s += __shfl_xor(s, off, 64);
    if (lane == 0) (is_e ? esq : xsq)[row] = s;
  }

  grid_bar(bar, bar + 1, 1);

  // ---------------- phase G: r9's pmin GEMM body, grid-strided over 4096 tiles ------
  // (A=E, B=X swapped operands; C/D: x-row = lane&31, e-col in reg index r.)
  const int li = lane & 15;
  const int lh = (lane >> 4) & 1;
  const int lq2 = lane >> 5;
  const int r_st = lane >> 2;
  const int kp_st = ((lane & 3) - (r_st >> 1)) & 3;
  const int sw_k0 = (li * 4 + ((lq2 + (li >> 1)) & 3)) * 8;
  const int sw_k1 = (li * 4 + ((2 + lq2 + (li >> 1)) & 3)) * 8;

  for (int t = blockIdx.x; t < 4096; t += NBLK) {
    const int nb = (t & 7) * 8 + ((t >> 3) & 7);
    const int mb = t >> 6;
    const int m0 = mb * 128, n0 = nb * 128;  // m = x-rows, n = codes
    const int wn = (wid >> 1) * 64, wm = (wid & 1) * 64;

    f32x16 acc[2][2];  // [et][xt]
#pragma unroll
    for (int a = 0; a < 2; ++a)
#pragma unroll
      for (int b = 0; b < 2; ++b)
#pragma unroll
        for (int r = 0; r < 16; ++r) acc[a][b][r] = 0.0f;

    const int eseg = (wn >> 4) + lh;
    const int xseg = (wm >> 4) + lh;

    for (int kc = 0; kc < 4; ++kc) {
      const int k0 = kc * 64;
      __syncthreads();
#pragma unroll
      for (int j = 0; j < 8; ++j) {  // 32 seg-loads over 4 waves
        const int tt = j * 4 + wid;
        const int tsel = tt >> 4;  // 0=E 1=X
        const int u = tt & 15;
        const int ksl = u >> 3, seg = u & 7;
        const int rowbase = (tsel ? m0 : n0) + seg * 16 + r_st;
        const unsigned short* src = tsel ? X0p : E0p;
        load_lds16(src + (size_t)rowbase * K_TOT + k0 + ksl * 32 + kp_st * 8,
                   &lds[tsel * 8192 + ksl * 4096 + seg * 512]);
      }
      __syncthreads();

#pragma unroll
      for (int ksl = 0; ksl < 2; ++ksl) {
        const unsigned short* Eb = &lds[ksl * 4096];
        const unsigned short* Xb = &lds[8192 + ksl * 4096];
        f16x8 ef[2][2];
#pragma unroll
        for (int et = 0; et < 2; ++et) {
          const unsigned short* eb = Eb + (eseg + et * 2) * 512;
          ef[et][0] = *(const f16x8*)(eb + sw_k0);
          ef[et][1] = *(const f16x8*)(eb + sw_k1);
        }
#pragma unroll
        for (int xt = 0; xt < 2; ++xt) {
          const unsigned short* xb = Xb + (xseg + xt * 2) * 512;
          f16x8 xf0 = *(const f16x8*)(xb + sw_k0);
          f16x8 xf1 = *(const f16x8*)(xb + sw_k1);
#pragma unroll
          for (int et = 0; et < 2; ++et) {
            f32x16 c = acc[et][xt];
            c = __builtin_amdgcn_mfma_f32_32x32x16_f16(ef[et][0], xf0, c, 0, 0, 0);
            c = __builtin_amdgcn_mfma_f32_32x32x16_f16(ef[et][1], xf1, c, 0, 0, 0);
            acc[et][xt] = c;
          }
        }
      }
    }

    // epilogue: d~ = ||e||^2 - 2 x.e ; per-(row,cell16) min, in-lane over r
    float es[2][16];
#pragma unroll
    for (int et = 0; et < 2; ++et)
#pragma unroll
      for (int r = 0; r < 16; ++r)
        es[et][r] = esq[n0 + wn + et * 32 + (r & 3) + 8 * (r >> 2) + 4 * lq2];

#pragma unroll
    for (int xt = 0; xt < 2; ++xt) {
      unsigned short outv[4];
#pragma unroll
      for (int et = 0; et < 2; ++et) {
#pragma unroll
        for (int cell = 0; cell < 2; ++cell) {
          float mval = 3.4e38f;
#pragma unroll
          for (int rr = 0; rr < 8; ++rr) {
            const int r = cell * 8 + rr;
            mval = fminf(mval, es[et][r] - 2.0f * acc[et][xt][r]);
          }
          mval = fminf(mval, __shfl_xor(mval, 32, 64));
          outv[et * 2 + cell] = __half_as_ushort(__float2half_rd(mval));
        }
      }
      if (lq2 == 0) {
        const int xrow = m0 + wm + xt * 32 + (lane & 31);
        *reinterpret_cast<ushort4*>(&pmin[(size_t)xrow * 512 + ((n0 + wn) >> 4)]) =
            *reinterpret_cast<ushort4*>(outv);
      }
    }
  }

  grid_bar(bar, bar + 1, 2);

  // ---------------- phase R: r9's refine + fused gather, grid-strided rows ----------
  for (int row = blockIdx.x * 4 + wid; row < 8192; row += NBLK * 4) {
    const unsigned short* pm = pmin + (size_t)row * 512 + lane * 8;
    int4 raw = *reinterpret_cast<const int4*>(pm);
    unsigned short cu[8];
    *reinterpret_cast<int4*>(cu) = raw;
    float cv[8];
#pragma unroll
    for (int j = 0; j < 8; ++j) cv[j] = __half2float(__ushort_as_half(cu[j]));
    float lm = cv[0];
#pragma unroll
    for (int j = 1; j < 8; ++j) lm = fminf(lm, cv[j]);
#pragma unroll
    for (int off = 1; off < 64; off <<= 1) lm = fminf(lm, __shfl_xor(lm, off, 64));

    const float thr = lm + sqrtf(xsq[row]) * (96.0f / 1024.0f) + 1.2f;

    const int c = lane & 15, q = lane >> 4;
    const float* xp = x + (size_t)row * K_TOT + q * 64;

    double bd = 1e300;
    int bidx = 1 << 30;
#pragma unroll
    for (int j = 0; j < 8; ++j) {
      unsigned long long mask = __ballot(cv[j] < thr);
      while (mask) {
        const int b = __ffsll((long long)mask) - 1;
        mask &= mask - 1;
        const int cell = b * 8 + j;
        const int col = cell * 16 + c;
        const float* ep = embed + (size_t)col * K_TOT + q * 64;
        double dd = 0.0;
#pragma unroll
        for (int i = 0; i < 16; ++i) {
          float4 e4 = reinterpret_cast<const float4*>(ep)[i];
          float4 x4 = reinterpret_cast<const float4*>(xp)[i];
          double d0 = (double)x4.x - (double)e4.x;
          double d1 = (double)x4.y - (double)e4.y;
          double d2 = (double)x4.z - (double)e4.z;
          double d3 = (double)x4.w - (double)e4.w;
          dd += d0 * d0 + d1 * d1 + d2 * d2 + d3 * d3;
        }
        dd += shfl_xor_d(dd, 16);
        dd += shfl_xor_d(dd, 32);
        int ci = col;
#pragma unroll
        for (int off = 1; off < 16; off <<= 1) {
          double od = shfl_xor_d(dd, off);
          int oi = __shfl_xor(ci, off, 64);
          if (od < dd || (od == dd && oi < ci)) { dd = od; ci = oi; }
        }
        if (dd < bd || (dd == bd && ci < bidx)) { bd = dd; bidx = ci; }
      }
    }

    reinterpret_cast<float4*>(out)[(size_t)row * 64 + lane] =
        reinterpret_cast<const float4*>(embed)[(size_t)bidx * 64 + lane];
    if (lane == 0) out[(size_t)M_TOT * K_TOT + row] = (float)bidx;
  }
}

// ================= fallback (round-1 fp32 path, known-correct) =================
#define BM 32
#define BN 64
#define KC 32
#define NQ 2
#define NPQ (N_TOT / NQ)
#define SB 72

__global__ __launch_bounds__(256) void esq_kernel(const float* __restrict__ embed,
                                                  float* __restrict__ esq) {
  const int lane = threadIdx.x & 63;
  const int wave = threadIdx.x >> 6;
  const int code = blockIdx.x * 4 + wave;
  float4 v = reinterpret_cast<const float4*>(embed + (size_t)code * K_TOT)[lane];
  float s = v.x * v.x + v.y * v.y + v.z * v.z + v.w * v.w;
#pragma unroll
  for (int off = 32; off > 0; off >>= 1) s += __shfl_xor(s, off, 64);
  if (lane == 0) esq[code] = s;
}

__global__ __launch_bounds__(256, 2) void argmin_kernel(
    const float* __restrict__ x, const float* __restrict__ embed,
    const float* __restrict__ esq, float* __restrict__ pval, int* __restrict__ pidx) {
  __shared__ float A[K_TOT][BM];
  __shared__ float Bs[KC][SB];
  const int tid = threadIdx.x;
  const int tx = tid & 15;
  const int ty = tid >> 4;
  const int q = blockIdx.x & 1;
  const int mb = blockIdx.x >> 1;
  const int m0 = mb * BM;
  const int nq0 = q * NPQ;
#pragma unroll
  for (int it = 0; it < 8; ++it) {
    int idx = it * 256 + tid;
    int row = idx >> 6;
    int k4 = idx & 63;
    float4 v = reinterpret_cast<const float4*>(x + (size_t)(m0 + row) * K_TOT)[k4];
    A[k4 * 4 + 0][row] = v.x; A[k4 * 4 + 1][row] = v.y;
    A[k4 * 4 + 2][row] = v.z; A[k4 * 4 + 3][row] = v.w;
  }
  float minv[2]; int mini[2];
#pragma unroll
  for (int r = 0; r < 2; ++r) { minv[r] = 3.4e38f; mini[r] = 0; }
  for (int ns = 0; ns < NPQ / BN; ++ns) {
    const int n0 = nq0 + ns * BN;
    float acc[2][4];
#pragma unroll
    for (int r = 0; r < 2; ++r)
#pragma unroll
      for (int c = 0; c < 4; ++c) acc[r][c] = 0.0f;
    for (int kc = 0; kc < K_TOT / KC; ++kc) {
      const int k0 = kc * KC;
      __syncthreads();
#pragma unroll
      for (int it = 0; it < 2; ++it) {
        int idx = it * 256 + tid;
        int nl = idx >> 3;
        int k4 = idx & 7;
        float4 v = reinterpret_cast<const float4*>(embed + (size_t)(n0 + nl) * K_TOT + k0)[k4];
        Bs[k4 * 4 + 0][nl] = v.x; Bs[k4 * 4 + 1][nl] = v.y;
        Bs[k4 * 4 + 2][nl] = v.z; Bs[k4 * 4 + 3][nl] = v.w;
      }
      __syncthreads();
#pragma unroll
      for (int kk = 0; kk < KC; ++kk) {
        float2 a = *reinterpret_cast<const float2*>(&A[k0 + kk][ty * 2]);
        float4 b = *reinterpret_cast<const float4*>(&Bs[kk][tx * 4]);
        acc[0][0] += a.x * b.x; acc[0][1] += a.x * b.y;
        acc[0][2] += a.x * b.z; acc[0][3] += a.x * b.w;
        acc[1][0] += a.y * b.x; acc[1][1] += a.y * b.y;
        acc[1][2] += a.y * b.z; acc[1][3] += a.y * b.w;
      }
    }
    float4 es = *reinterpret_cast<const float4*>(&esq[n0 + tx * 4]);
    float e[4] = {es.x, es.y, es.z, es.w};
#pragma unroll
    for (int r = 0; r < 2; ++r)
#pragma unroll
      for (int c = 0; c < 4; ++c) {
        float d = e[c] - 2.0f * acc[r][c];
        int id = n0 + tx * 4 + c;
        if (d < minv[r]) { minv[r] = d; mini[r] = id; }
      }
  }
#pragma unroll
  for (int r = 0; r < 2; ++r) {
    float v = minv[r]; int i = mini[r];
#pragma unroll
    for (int off = 1; off < 16; off <<= 1) {
      float vo = __shfl_xor(v, off, 64);
      int io = __shfl_xor(i, off, 64);
      if (vo < v || (vo == v && io < i)) { v = vo; i = io; }
    }
    if (tx == 0) {
      int row = m0 + ty * 2 + r;
      pval[q * M_TOT + row] = v;
      pidx[q * M_TOT + row] = i;
    }
  }
}

__global__ __launch_bounds__(256) void gather_kernel(
    const float* __restrict__ embed, const float* __restrict__ pval,
    const int* __restrict__ pidx, float* __restrict__ out) {
  const int row = blockIdx.x;
  float bv = pval[row]; int bi = pidx[row];
#pragma unroll
  for (int qq = 1; qq < NQ; ++qq) {
    float v = pval[qq * M_TOT + row];
    int i = pidx[qq * M_TOT + row];
    if (v < bv || (v == bv && i < bi)) { bv = v; bi = i; }
  }
  out[(size_t)row * K_TOT + threadIdx.x] = embed[(size_t)bi * K_TOT + threadIdx.x];
  if (threadIdx.x == 0) out[(size_t)M_TOT * K_TOT + row] = (float)bi;
}

// ================= launch =================
extern "C" void kernel_launch(void* const* d_in, const int* in_sizes, int n_in,
                              void* d_out, int out_size, void* d_ws, size_t ws_size,
                              hipStream_t stream) {
  const float* x = (const float*)d_in[0];
  const float* embed = (const float*)d_in[1];
  float* out = (float*)d_out;
  char* ws = (char*)d_ws;

  const size_t HALF_BYTES = (size_t)M_TOT * K_TOT * 2;   // 4 MB per fp16 tensor
  const size_t PMIN_BYTES = (size_t)M_TOT * 512 * 2;     // 8 MB
  const size_t need = (1u << 20) + 2 * HALF_BYTES + PMIN_BYTES;  // ~17 MB

  if (ws_size >= need) {
    unsigned* bar = (unsigned*)ws;                        // 64 B (memset below)
    float* xsq = (float*)(ws + 65536);                    // 32 KB
    float* esq = (float*)(ws + 65536 + 32768);            // 32 KB
    unsigned short* X0p = (unsigned short*)(ws + (1u << 20));
    unsigned short* E0p = (unsigned short*)(ws + (1u << 20) + HALF_BYTES);
    unsigned short* pmin = (unsigned short*)(ws + (1u << 20) + 2 * HALF_BYTES);
    hipMemsetAsync(bar, 0, 64, stream);  // barrier cnt/sense = 0 (ws is poisoned)
    fused_kernel<<<NBLK, 256, 0, stream>>>(x, embed, X0p, E0p, xsq, esq, pmin, bar, out);
  } else {
    float* esq = (float*)ws;
    float* pval = (float*)(ws + 32768);
    int* pidx = (int*)(ws + 32768 + NQ * 32768);
    esq_kernel<<<2048, 256, 0, stream>>>(embed, esq);
    argmin_kernel<<<512, 256, 0, stream>>>(x, embed, esq, pval, pidx);
    gather_kernel<<<M_TOT, 256, 0, stream>>>(embed, pval, pidx, out);
  }
}

// Round 11
// 151.829 us; speedup vs baseline: 2.5852x; 2.5852x over previous
//
#include <hip/hip_runtime.h>
#include <hip/hip_fp16.h>

typedef __attribute__((ext_vector_type(8))) _Float16 f16x8;
typedef __attribute__((ext_vector_type(16))) float f32x16;

#define M_TOT 8192
#define N_TOT 8192
#define K_TOT 256

__device__ __forceinline__ void load_lds16(const void* g, void* l) {
  __builtin_amdgcn_global_load_lds(
      (const __attribute__((address_space(1))) unsigned int*)g,
      (__attribute__((address_space(3))) unsigned int*)l, 16, 0, 0);
}
__device__ __forceinline__ double shfl_xor_d(double v, int m) {
  unsigned long long u = (unsigned long long)__double_as_longlong(v);
  unsigned lo = (unsigned)u, hi = (unsigned)(u >> 32);
  lo = __shfl_xor(lo, m, 64);
  hi = __shfl_xor(hi, m, 64);
  return __longlong_as_double((long long)((((unsigned long long)hi) << 32) | lo));
}

// ---------- prep: fp16 convert (row-major) + row sq-norms ----------
__global__ __launch_bounds__(256) void prep_kernel(
    const float* __restrict__ x, const float* __restrict__ embed,
    unsigned short* __restrict__ X0p, unsigned short* __restrict__ E0p,
    float* __restrict__ xsq, float* __restrict__ esq) {
  const int bid = blockIdx.x;
  const bool is_e = bid >= 2048;
  const int lb = is_e ? bid - 2048 : bid;
  const int t = lb * 256 + threadIdx.x;  // 4 elems per thread; wave == row
  const float* __restrict__ in = is_e ? embed : x;
  unsigned short* __restrict__ p0 = is_e ? E0p : X0p;
  float* __restrict__ sq = is_e ? esq : xsq;

  float4 v = reinterpret_cast<const float4*>(in)[t];
  float f[4] = {v.x, v.y, v.z, v.w};
  unsigned short h[4];
#pragma unroll
  for (int c = 0; c < 4; ++c) h[c] = __half_as_ushort(__float2half_rn(f[c]));
  ushort4 o = {h[0], h[1], h[2], h[3]};
  reinterpret_cast<ushort4*>(p0)[t] = o;

  const int lane = threadIdx.x & 63;
  float s = f[0] * f[0] + f[1] * f[1] + f[2] * f[2] + f[3] * f[3];
#pragma unroll
  for (int off = 32; off > 0; off >>= 1) s += __shfl_xor(s, off, 64);
  if (lane == 0) sq[lb * 4 + (threadIdx.x >> 6)] = s;
}

// ---------- phase-1: single-pass fp16 MFMA, swapped operands (A=E, B=X) ----------
// r9 body verified. NEW (r11): de-phase co-resident blocks. Theory: the 3
// blocks/CU launch simultaneously and run identical chunk loops -> their
// vmcnt(0) barrier drains align in time, so nothing overlaps (serial-sum
// behavior seen r2..r9). A one-time ~1/3-chunk-period skew per block slot
// (slot ~ bid>>8 among the first 768 dispatched) staggers the phases so one
// block's MFMA covers another's drain. Zero correctness impact.
__global__ __launch_bounds__(256, 3) void mfma_pmin_kernel(
    const unsigned short* __restrict__ X0p, const unsigned short* __restrict__ E0p,
    const float* __restrict__ esq, unsigned short* __restrict__ pmin) {
  __shared__ unsigned short lds[16384];  // 32 KB: E [ksl][seg] at 0, X at 8192

  const int tid = threadIdx.x;
  const int wid = tid >> 6;
  const int lane = tid & 63;
  const int li = lane & 15;
  const int lh = (lane >> 4) & 1;
  const int lq2 = lane >> 5;

  const int bid = blockIdx.x;

  // ---- desync preamble: skew initial co-residents by ~1920 cyc per slot ----
  const int slot = bid >> 8;  // first 768 dispatched -> slots 0,1,2
  if (slot < 3) {
    for (int s = 0; s < slot * 2; ++s) __builtin_amdgcn_s_sleep(15);  // 15*64 cyc each
  }

  const int nb = (bid & 7) * 8 + ((bid >> 3) & 7);  // XCD-sharded codes
  const int mb = bid >> 6;
  const int m0 = mb * 128, n0 = nb * 128;  // m = x-rows, n = codes
  const int wn = (wid >> 1) * 64, wm = (wid & 1) * 64;

  const int r_st = lane >> 2;
  const int kp_st = ((lane & 3) - (r_st >> 1)) & 3;
  const int sw_k0 = (li * 4 + ((lq2 + (li >> 1)) & 3)) * 8;
  const int sw_k1 = (li * 4 + ((2 + lq2 + (li >> 1)) & 3)) * 8;

  f32x16 acc[2][2];  // [et][xt]
#pragma unroll
  for (int a = 0; a < 2; ++a)
#pragma unroll
    for (int b = 0; b < 2; ++b)
#pragma unroll
      for (int r = 0; r < 16; ++r) acc[a][b][r] = 0.0f;

  const int eseg = (wn >> 4) + lh;  // + et*2
  const int xseg = (wm >> 4) + lh;  // + xt*2

  for (int kc = 0; kc < 4; ++kc) {
    const int k0 = kc * 64;
    __syncthreads();
#pragma unroll
    for (int j = 0; j < 8; ++j) {  // 32 seg-loads over 4 waves
      const int tt = j * 4 + wid;
      const int tsel = tt >> 4;    // 0=E 1=X
      const int u = tt & 15;
      const int ksl = u >> 3, seg = u & 7;
      const int rowbase = (tsel ? m0 : n0) + seg * 16 + r_st;
      const unsigned short* src = tsel ? X0p : E0p;
      load_lds16(src + (size_t)rowbase * K_TOT + k0 + ksl * 32 + kp_st * 8,
                 &lds[tsel * 8192 + ksl * 4096 + seg * 512]);
    }
    __syncthreads();

#pragma unroll
    for (int ksl = 0; ksl < 2; ++ksl) {
      const unsigned short* Eb = &lds[ksl * 4096];
      const unsigned short* Xb = &lds[8192 + ksl * 4096];
      f16x8 ef[2][2];
#pragma unroll
      for (int et = 0; et < 2; ++et) {
        const unsigned short* eb = Eb + (eseg + et * 2) * 512;
        ef[et][0] = *(const f16x8*)(eb + sw_k0);
        ef[et][1] = *(const f16x8*)(eb + sw_k1);
      }
#pragma unroll
      for (int xt = 0; xt < 2; ++xt) {
        const unsigned short* xb = Xb + (xseg + xt * 2) * 512;
        f16x8 xf0 = *(const f16x8*)(xb + sw_k0);
        f16x8 xf1 = *(const f16x8*)(xb + sw_k1);
#pragma unroll
        for (int et = 0; et < 2; ++et) {
          f32x16 c = acc[et][xt];
          c = __builtin_amdgcn_mfma_f32_32x32x16_f16(ef[et][0], xf0, c, 0, 0, 0);
          c = __builtin_amdgcn_mfma_f32_32x32x16_f16(ef[et][1], xf1, c, 0, 0, 0);
          acc[et][xt] = c;
        }
      }
    }
  }

  // ---- epilogue: d~ = ||e||^2 - 2 x.e ; per-(row,cell16) min, in-lane over r ----
  float es[2][16];
#pragma unroll
  for (int et = 0; et < 2; ++et)
#pragma unroll
    for (int r = 0; r < 16; ++r)
      es[et][r] = esq[n0 + wn + et * 32 + (r & 3) + 8 * (r >> 2) + 4 * lq2];

#pragma unroll
  for (int xt = 0; xt < 2; ++xt) {
    unsigned short outv[4];
#pragma unroll
    for (int et = 0; et < 2; ++et) {
#pragma unroll
      for (int cell = 0; cell < 2; ++cell) {  // cell0: r 0..7, cell1: r 8..15
        float mval = 3.4e38f;
#pragma unroll
        for (int rr = 0; rr < 8; ++rr) {
          const int r = cell * 8 + rr;
          mval = fminf(mval, es[et][r] - 2.0f * acc[et][xt][r]);
        }
        mval = fminf(mval, __shfl_xor(mval, 32, 64));  // combine lq2 col-halves
        outv[et * 2 + cell] = __half_as_ushort(__float2half_rd(mval));
      }
    }
    if (lq2 == 0) {
      const int xrow = m0 + wm + xt * 32 + (lane & 31);
      *reinterpret_cast<ushort4*>(&pmin[(size_t)xrow * 512 + ((n0 + wn) >> 4)]) =
          *reinterpret_cast<ushort4*>(outv);
    }
  }
}

// ---------- phase-2: per-row exact refine (fp64, lane-parallel) + fused gather ----------
__global__ __launch_bounds__(256) void refine_gather_kernel(
    const float* __restrict__ x, const float* __restrict__ embed,
    const float* __restrict__ xsq, const unsigned short* __restrict__ pmin,
    float* __restrict__ out) {
  const int row = blockIdx.x * 4 + (threadIdx.x >> 6);
  const int lane = threadIdx.x & 63;

  const unsigned short* pm = pmin + (size_t)row * 512 + lane * 8;
  int4 raw = *reinterpret_cast<const int4*>(pm);
  unsigned short cu[8];
  *reinterpret_cast<int4*>(cu) = raw;
  float cv[8];
#pragma unroll
  for (int j = 0; j < 8; ++j) cv[j] = __half2float(__ushort_as_half(cu[j]));
  float lm = cv[0];
#pragma unroll
  for (int j = 1; j < 8; ++j) lm = fminf(lm, cv[j]);
#pragma unroll
  for (int off = 1; off < 64; off <<= 1) lm = fminf(lm, __shfl_xor(lm, off, 64));

  const float thr = lm + sqrtf(xsq[row]) * (96.0f / 1024.0f) + 1.2f;

  const int c = lane & 15, q = lane >> 4;
  const float* xp = x + (size_t)row * K_TOT + q * 64;

  double bd = 1e300;
  int bidx = 1 << 30;
#pragma unroll
  for (int j = 0; j < 8; ++j) {
    unsigned long long mask = __ballot(cv[j] < thr);
    while (mask) {
      const int b = __ffsll((long long)mask) - 1;
      mask &= mask - 1;
      const int cell = b * 8 + j;
      const int col = cell * 16 + c;
      const float* ep = embed + (size_t)col * K_TOT + q * 64;
      double dd = 0.0;
#pragma unroll
      for (int i = 0; i < 16; ++i) {
        float4 e4 = reinterpret_cast<const float4*>(ep)[i];
        float4 x4 = reinterpret_cast<const float4*>(xp)[i];
        double d0 = (double)x4.x - (double)e4.x;
        double d1 = (double)x4.y - (double)e4.y;
        double d2 = (double)x4.z - (double)e4.z;
        double d3 = (double)x4.w - (double)e4.w;
        dd += d0 * d0 + d1 * d1 + d2 * d2 + d3 * d3;
      }
      dd += shfl_xor_d(dd, 16);  // combine q-partials
      dd += shfl_xor_d(dd, 32);
      int ci = col;
#pragma unroll
      for (int off = 1; off < 16; off <<= 1) {  // c-reduce with index
        double od = shfl_xor_d(dd, off);
        int oi = __shfl_xor(ci, off, 64);
        if (od < dd || (od == dd && oi < ci)) { dd = od; ci = oi; }
      }
      if (dd < bd || (dd == bd && ci < bidx)) { bd = dd; bidx = ci; }
    }
  }

  // fused gather + index write (bidx is wave-uniform)
  reinterpret_cast<float4*>(out)[(size_t)row * 64 + lane] =
      reinterpret_cast<const float4*>(embed)[(size_t)bidx * 64 + lane];
  if (lane == 0) out[(size_t)M_TOT * K_TOT + row] = (float)bidx;
}

// ================= fallback (round-1 fp32 path, known-correct) =================
#define BM 32
#define BN 64
#define KC 32
#define NQ 2
#define NPQ (N_TOT / NQ)
#define SB 72

__global__ __launch_bounds__(256) void esq_kernel(const float* __restrict__ embed,
                                                  float* __restrict__ esq) {
  const int lane = threadIdx.x & 63;
  const int wave = threadIdx.x >> 6;
  const int code = blockIdx.x * 4 + wave;
  float4 v = reinterpret_cast<const float4*>(embed + (size_t)code * K_TOT)[lane];
  float s = v.x * v.x + v.y * v.y + v.z * v.z + v.w * v.w;
#pragma unroll
  for (int off = 32; off > 0; off >>= 1) s += __shfl_xor(s, off, 64);
  if (lane == 0) esq[code] = s;
}

__global__ __launch_bounds__(256, 2) void argmin_kernel(
    const float* __restrict__ x, const float* __restrict__ embed,
    const float* __restrict__ esq, float* __restrict__ pval, int* __restrict__ pidx) {
  __shared__ float A[K_TOT][BM];
  __shared__ float Bs[KC][SB];
  const int tid = threadIdx.x;
  const int tx = tid & 15;
  const int ty = tid >> 4;
  const int q = blockIdx.x & 1;
  const int mb = blockIdx.x >> 1;
  const int m0 = mb * BM;
  const int nq0 = q * NPQ;
#pragma unroll
  for (int it = 0; it < 8; ++it) {
    int idx = it * 256 + tid;
    int row = idx >> 6;
    int k4 = idx & 63;
    float4 v = reinterpret_cast<const float4*>(x + (size_t)(m0 + row) * K_TOT)[k4];
    A[k4 * 4 + 0][row] = v.x; A[k4 * 4 + 1][row] = v.y;
    A[k4 * 4 + 2][row] = v.z; A[k4 * 4 + 3][row] = v.w;
  }
  float minv[2]; int mini[2];
#pragma unroll
  for (int r = 0; r < 2; ++r) { minv[r] = 3.4e38f; mini[r] = 0; }
  for (int ns = 0; ns < NPQ / BN; ++ns) {
    const int n0 = nq0 + ns * BN;
    float acc[2][4];
#pragma unroll
    for (int r = 0; r < 2; ++r)
#pragma unroll
      for (int c = 0; c < 4; ++c) acc[r][c] = 0.0f;
    for (int kc = 0; kc < K_TOT / KC; ++kc) {
      const int k0 = kc * KC;
      __syncthreads();
#pragma unroll
      for (int it = 0; it < 2; ++it) {
        int idx = it * 256 + tid;
        int nl = idx >> 3;
        int k4 = idx & 7;
        float4 v = reinterpret_cast<const float4*>(embed + (size_t)(n0 + nl) * K_TOT + k0)[k4];
        Bs[k4 * 4 + 0][nl] = v.x; Bs[k4 * 4 + 1][nl] = v.y;
        Bs[k4 * 4 + 2][nl] = v.z; Bs[k4 * 4 + 3][nl] = v.w;
      }
      __syncthreads();
#pragma unroll
      for (int kk = 0; kk < KC; ++kk) {
        float2 a = *reinterpret_cast<const float2*>(&A[k0 + kk][ty * 2]);
        float4 b = *reinterpret_cast<const float4*>(&Bs[kk][tx * 4]);
        acc[0][0] += a.x * b.x; acc[0][1] += a.x * b.y;
        acc[0][2] += a.x * b.z; acc[0][3] += a.x * b.w;
        acc[1][0] += a.y * b.x; acc[1][1] += a.y * b.y;
        acc[1][2] += a.y * b.z; acc[1][3] += a.y * b.w;
      }
    }
    float4 es = *reinterpret_cast<const float4*>(&esq[n0 + tx * 4]);
    float e[4] = {es.x, es.y, es.z, es.w};
#pragma unroll
    for (int r = 0; r < 2; ++r)
#pragma unroll
      for (int c = 0; c < 4; ++c) {
        float d = e[c] - 2.0f * acc[r][c];
        int id = n0 + tx * 4 + c;
        if (d < minv[r]) { minv[r] = d; mini[r] = id; }
      }
  }
#pragma unroll
  for (int r = 0; r < 2; ++r) {
    float v = minv[r]; int i = mini[r];
#pragma unroll
    for (int off = 1; off < 16; off <<= 1) {
      float vo = __shfl_xor(v, off, 64);
      int io = __shfl_xor(i, off, 64);
      if (vo < v || (vo == v && io < i)) { v = vo; i = io; }
    }
    if (tx == 0) {
      int row = m0 + ty * 2 + r;
      pval[q * M_TOT + row] = v;
      pidx[q * M_TOT + row] = i;
    }
  }
}

__global__ __launch_bounds__(256) void gather_kernel(
    const float* __restrict__ embed, const float* __restrict__ pval,
    const int* __restrict__ pidx, float* __restrict__ out) {
  const int row = blockIdx.x;
  float bv = pval[row]; int bi = pidx[row];
#pragma unroll
  for (int qq = 1; qq < NQ; ++qq) {
    float v = pval[qq * M_TOT + row];
    int i = pidx[qq * M_TOT + row];
    if (v < bv || (v == bv && i < bi)) { bv = v; bi = i; }
  }
  out[(size_t)row * K_TOT + threadIdx.x] = embed[(size_t)bi * K_TOT + threadIdx.x];
  if (threadIdx.x == 0) out[(size_t)M_TOT * K_TOT + row] = (float)bi;
}

// ================= launch =================
extern "C" void kernel_launch(void* const* d_in, const int* in_sizes, int n_in,
                              void* d_out, int out_size, void* d_ws, size_t ws_size,
                              hipStream_t stream) {
  const float* x = (const float*)d_in[0];
  const float* embed = (const float*)d_in[1];
  float* out = (float*)d_out;
  char* ws = (char*)d_ws;

  const size_t HALF_BYTES = (size_t)M_TOT * K_TOT * 2;   // 4 MB per fp16 tensor
  const size_t PMIN_BYTES = (size_t)M_TOT * 512 * 2;     // 8 MB
  const size_t need = (1u << 20) + 2 * HALF_BYTES + PMIN_BYTES;  // ~17 MB

  if (ws_size >= need) {
    float* xsq = (float*)ws;                             // 32 KB
    float* esq = (float*)(ws + 32768);                   // 32 KB
    unsigned short* X0p = (unsigned short*)(ws + (1u << 20));
    unsigned short* E0p = (unsigned short*)(ws + (1u << 20) + HALF_BYTES);
    unsigned short* pmin = (unsigned short*)(ws + (1u << 20) + 2 * HALF_BYTES);
    prep_kernel<<<4096, 256, 0, stream>>>(x, embed, X0p, E0p, xsq, esq);
    mfma_pmin_kernel<<<4096, 256, 0, stream>>>(X0p, E0p, esq, pmin);
    refine_gather_kernel<<<2048, 256, 0, stream>>>(x, embed, xsq, pmin, out);
  } else {
    float* esq = (float*)ws;
    float* pval = (float*)(ws + 32768);
    int* pidx = (int*)(ws + 32768 + NQ * 32768);
    esq_kernel<<<2048, 256, 0, stream>>>(embed, esq);
    argmin_kernel<<<512, 256, 0, stream>>>(x, embed, esq, pval, pidx);
    gather_kernel<<<M_TOT, 256, 0, stream>>>(embed, pval, pidx, out);
  }
}